// Round 18
// baseline (217.000 us; speedup 1.0000x reference)
//
#include <hip/hip_runtime.h>

typedef unsigned short u16;
typedef unsigned int u32;
typedef short bf16x8 __attribute__((ext_vector_type(8)));
typedef float f32x4 __attribute__((ext_vector_type(4)));

static constexpr int LS = 2048;   // seq len
static constexpr int DM = 1024;   // d_model
static constexpr int DI = 2048;   // d_inner
static constexpr int DSn = 16;    // d_state
static constexpr int DTRk = 64;   // dt_rank
static constexpr int MR = 4096;   // B*L rows
static constexpr int NCH = 64;    // scan chunks
static constexpr int CL = LS / NCH;  // 32 timesteps per chunk
static constexpr float L2E = 1.44269504f;

#define DEV __device__ __forceinline__

DEV u16 f2bf(float f) {
  u32 u = __float_as_uint(f);
  u32 r = (u + 0x7FFF + ((u >> 16) & 1)) >> 16;
  return (u16)r;
}
DEV float bf2f(u16 h) { return __uint_as_float(((u32)h) << 16); }

DEV void gload16(const u16* g, u16* l) {
  __builtin_amdgcn_global_load_lds((const __attribute__((address_space(1))) u32*)g,
                                   (__attribute__((address_space(3))) u32*)l, 16, 0, 0);
}

DEV void bar() { asm volatile("s_barrier" ::: "memory"); }

// powers tree: dst[j] = base^(j+1), depth 4, 15 muls
#define CALC_POWERS(dst, basev)                                              \
  do {                                                                       \
    const float e1_ = (basev);                                               \
    const float e2_ = e1_ * e1_, e3_ = e2_ * e1_, e4_ = e2_ * e2_;           \
    const float e5_ = e4_ * e1_, e6_ = e4_ * e2_, e7_ = e4_ * e3_,           \
                e8_ = e4_ * e4_;                                             \
    dst[0] = e1_; dst[1] = e2_; dst[2] = e3_; dst[3] = e4_;                  \
    dst[4] = e5_; dst[5] = e6_; dst[6] = e7_; dst[7] = e8_;                  \
    dst[8] = e8_ * e1_;  dst[9] = e8_ * e2_;  dst[10] = e8_ * e3_;           \
    dst[11] = e8_ * e4_; dst[12] = e8_ * e5_; dst[13] = e8_ * e6_;           \
    dst[14] = e8_ * e7_; dst[15] = e8_ * e8_;                                \
  } while (0)

// ---------------- fused RMSNorm (1 row/block) + weight converts (float4-wide) ----------------
__global__ __launch_bounds__(256) void cvt_norm(const float* __restrict__ x,
                                                const float* __restrict__ w,
                                                const float* __restrict__ W_in,
                                                const float* __restrict__ W_out,
                                                const float* __restrict__ W_dt,
                                                const float* __restrict__ W_xp,
                                                u16* __restrict__ xn,
                                                u16* __restrict__ Win_b,
                                                u16* __restrict__ Wout_b,
                                                u16* __restrict__ Wdt_b,
                                                u16* __restrict__ Wxp_b) {
  const int row = blockIdx.x;
  const int tid = threadIdx.x;
  {  // rmsnorm of row
    const float4 v = reinterpret_cast<const float4*>(x + (size_t)row * DM)[tid];
    float ss = v.x * v.x + v.y * v.y + v.z * v.z + v.w * v.w;
#pragma unroll
    for (int o = 32; o; o >>= 1) ss += __shfl_xor(ss, o);
    __shared__ float red[4];
    if ((tid & 63) == 0) red[tid >> 6] = ss;
    __syncthreads();
    const float tot = red[0] + red[1] + red[2] + red[3];
    const float scale = rsqrtf(tot * (1.0f / DM) + 1e-5f);
    const float4 wv = reinterpret_cast<const float4*>(w)[tid];
    ushort4 o4;
    o4.x = f2bf(v.x * scale * wv.x);
    o4.y = f2bf(v.y * scale * wv.y);
    o4.z = f2bf(v.z * scale * wv.z);
    o4.w = f2bf(v.w * scale * wv.w);
    *reinterpret_cast<ushort4*>(&xn[(size_t)row * DM + tid * 4]) = o4;
  }
  // weight converts, float4-wide grid-stride (all boundaries divisible by 4)
  const int Q0 = (4096 * 1024) / 4;
  const int Q1 = Q0 + (1024 * 2048) / 4;
  const int Q2 = Q1 + (2048 * 64) / 4;
  const int Q3 = Q2 + (128 * 2048) / 4;
  int q = blockIdx.x * 256 + tid;
  const int stride = gridDim.x * 256;
  for (; q < Q3; q += stride) {
    float4 v;
    u16* dst;
    int jj;
    if (q < Q0) {
      jj = q * 4;
      v = reinterpret_cast<const float4*>(W_in)[q];
      dst = Win_b + jj;
    } else if (q < Q1) {
      jj = (q - Q0) * 4;
      v = reinterpret_cast<const float4*>(W_out)[q - Q0];
      dst = Wout_b + jj;
    } else if (q < Q2) {
      jj = (q - Q1) * 4;
      v = reinterpret_cast<const float4*>(W_dt)[q - Q1];
      dst = Wdt_b + jj;
    } else {
      jj = (q - Q2) * 4;
      const int r = jj >> 11;
      if (r < 96) {
        v = reinterpret_cast<const float4*>(W_xp)[(r * 2048 + (jj & 2047)) / 4];
      } else {
        v = float4{0.f, 0.f, 0.f, 0.f};
      }
      dst = Wxp_b + jj;
    }
    ushort4 o4;
    o4.x = f2bf(v.x); o4.y = f2bf(v.y); o4.z = f2bf(v.z); o4.w = f2bf(v.w);
    *reinterpret_cast<ushort4*>(dst) = o4;
  }
}

// ================= 128x256 GEMM, BK=32, 16x16x32 MFMA, 2 blocks/CU =================
// 8 waves of 64x64 (2M x 4N). LDS: 2 superbuffers x 24KB = 48KB -> 2 blocks/CU.
// 1 barrier per K-tile. Swizzle slot = kq ^ ((row>>1)&3), inverse on global source.
// EPI 0: bf16 out at outB. EPI 1: bf16 partial at outB + z*MR*N (split-K over blockIdx.z).
template <int EPI>
__global__ __launch_bounds__(512, 4) void gemm128n256(const u16* __restrict__ A,
                                                      const u16* __restrict__ Bw,
                                                      int M, int N, int K, int Klen,
                                                      u16* __restrict__ outB) {
  __shared__ __align__(16) u16 SL[2 * 12288];  // 48 KB; super = A[0,4096) B[4096,12288) u16
  const int tid = threadIdx.x;
  const int lane = tid & 63;
  const int wid = tid >> 6;
  const int wr = wid >> 2;   // 0..1 (M half)
  const int wc = wid & 3;    // 0..3 (N quarter)
  const int lrow = lane & 15;
  const int kq = lane >> 4;  // 0..3

  const int nwg = gridDim.x * gridDim.y;
  int wg = blockIdx.y * gridDim.x + blockIdx.x;
  wg = (wg & 7) * (nwg >> 3) + (wg >> 3);
  const int bn = (wg % gridDim.x) * 256;
  const int bm = (wg / gridDim.x) * 128;
  const int koff = blockIdx.z * Klen;

  const int nt = Klen >> 5;  // BK=32

  f32x4 acc[4][4] = {};
  bf16x8 a[4], b[4];

  // staging indices (linear LDS dest, inverse-swizzled source)
  const int srA = tid >> 2;                       // A row 0..127
  const int slA = (tid & 3) ^ ((srA >> 1) & 3);   // source slot
  const int srB0 = tid >> 2, srB1 = 128 + (tid >> 2);  // B rows
  const int slB0 = (tid & 3) ^ ((srB0 >> 1) & 3);
  const int slB1 = (tid & 3) ^ ((srB1 >> 1) & 3);

#define STAGE_TILE(ktile, sup)                                                          \
  do {                                                                                  \
    const int k0_ = koff + (ktile) * 32;                                                \
    gload16(A + (size_t)(bm + srA) * K + k0_ + slA * 8, &SL[(sup) + tid * 8]);          \
    gload16(Bw + (size_t)(bn + srB0) * K + k0_ + slB0 * 8, &SL[(sup) + 4096 + tid * 8]);\
    gload16(Bw + (size_t)(bn + srB1) * K + k0_ + slB1 * 8, &SL[(sup) + 8192 + tid * 8]);\
  } while (0)

  // prologue: stage tile0 -> super0, publish
  STAGE_TILE(0, 0);
  asm volatile("s_waitcnt vmcnt(0)" ::: "memory");
  bar();

  for (int t = 0; t < nt; ++t) {
    const int cs = (t & 1) * 12288;
    const int ns = ((t + 1) & 1) * 12288;
    if (t + 1 < nt) STAGE_TILE(t + 1, ns);
    // fragment reads (swizzled) + 16 MFMA; compiler free to pipeline
#pragma unroll
    for (int m = 0; m < 4; ++m) {
      const int row = wr * 64 + m * 16 + lrow;
      a[m] = *reinterpret_cast<const bf16x8*>(
          &SL[cs + row * 32 + (kq ^ ((row >> 1) & 3)) * 8]);
    }
#pragma unroll
    for (int n = 0; n < 4; ++n) {
      const int row = wc * 64 + n * 16 + lrow;
      b[n] = *reinterpret_cast<const bf16x8*>(
          &SL[cs + 4096 + row * 32 + (kq ^ ((row >> 1) & 3)) * 8]);
    }
    __builtin_amdgcn_s_setprio(1);
#pragma unroll
    for (int m = 0; m < 4; ++m)
#pragma unroll
      for (int n = 0; n < 4; ++n)
        acc[m][n] = __builtin_amdgcn_mfma_f32_16x16x32_bf16(a[m], b[n], acc[m][n], 0, 0, 0);
    __builtin_amdgcn_s_setprio(0);
    if (t + 1 < nt) {
      asm volatile("s_waitcnt vmcnt(0)" ::: "memory");  // next tile landed
      bar();                                            // publish; reads of cs retired
    }
  }
#undef STAGE_TILE

  u16* dstB = (EPI == 0) ? outB : outB + (size_t)blockIdx.z * MR * N;
#pragma unroll
  for (int m = 0; m < 4; ++m)
#pragma unroll
    for (int n = 0; n < 4; ++n) {
      const int col = bn + wc * 64 + n * 16 + lrow;
#pragma unroll
      for (int rr = 0; rr < 4; ++rr) {
        const int row = bm + wr * 64 + m * 16 + kq * 4 + rr;
        dstB[(size_t)row * N + col] = f2bf(acc[m][n][rr]);
      }
    }
}

// out = sum of 4 bf16 partial slices + x (8-wide); p slices are MR*1024 bf16 each
__global__ __launch_bounds__(256) void outproj_reduce4b(const u16* __restrict__ p,
                                                        const float* __restrict__ x,
                                                        float* __restrict__ out) {
  const int id = blockIdx.x * 256 + threadIdx.x;  // over 4096*1024/8
  float acc8[8];
  const float4 x0 = reinterpret_cast<const float4*>(x)[id * 2];
  const float4 x1 = reinterpret_cast<const float4*>(x)[id * 2 + 1];
  acc8[0] = x0.x; acc8[1] = x0.y; acc8[2] = x0.z; acc8[3] = x0.w;
  acc8[4] = x1.x; acc8[5] = x1.y; acc8[6] = x1.z; acc8[7] = x1.w;
#pragma unroll
  for (int s = 0; s < 4; ++s) {
    const bf16x8 a = *reinterpret_cast<const bf16x8*>(
        &p[(size_t)s * MR * 1024 + (size_t)id * 8]);
#pragma unroll
    for (int j = 0; j < 8; ++j) acc8[j] += bf2f((u16)a[j]);
  }
  float4 o0 = {acc8[0], acc8[1], acc8[2], acc8[3]};
  float4 o1 = {acc8[4], acc8[5], acc8[6], acc8[7]};
  reinterpret_cast<float4*>(out)[id * 2] = o0;
  reinterpret_cast<float4*>(out)[id * 2 + 1] = o1;
}

// ---------------- MFMA GEMM 128^2 (m97 structure), dt-proj epilogue ----------------
__global__ __launch_bounds__(256) void gemm_dt(const u16* __restrict__ A,
                                               const u16* __restrict__ Bw,
                                               int M, int N, int K,
                                               u16* __restrict__ outB,
                                               const float* __restrict__ aux) {
  __shared__ __align__(16) u16 As[128 * 32];
  __shared__ __align__(16) u16 Bs[128 * 32];
  const int tid = threadIdx.x;
  const int lane = tid & 63;
  const int wid = tid >> 6;
  const int wr = wid >> 1, wc = wid & 1;
  const int nwg = gridDim.x * gridDim.y;
  int wg = blockIdx.y * gridDim.x + blockIdx.x;
  wg = (wg & 7) * (nwg >> 3) + (wg >> 3);
  const int bn = (wg % gridDim.x) * 128;
  const int bm = (wg / gridDim.x) * 128;
  const int r0 = tid >> 2;
  const int c0 = (tid & 3) * 8;
  const int lrow = lane & 15, kq = lane >> 4;

  f32x4 acc[4][4] = {};

  const u16* Ab = A + (size_t)bm * K;
  const u16* Bb = Bw + (size_t)bn * K;

  for (int k0 = 0; k0 < K; k0 += 32) {
    gload16(Ab + (size_t)r0 * K + k0 + c0, &As[r0 * 32 + c0]);
    gload16(Ab + (size_t)(r0 + 64) * K + k0 + c0, &As[(r0 + 64) * 32 + c0]);
    gload16(Bb + (size_t)r0 * K + k0 + c0, &Bs[r0 * 32 + c0]);
    gload16(Bb + (size_t)(r0 + 64) * K + k0 + c0, &Bs[(r0 + 64) * 32 + c0]);
    __syncthreads();
    bf16x8 af[4], bfr[4];
#pragma unroll
    for (int m = 0; m < 4; ++m)
      af[m] = *reinterpret_cast<const bf16x8*>(&As[(wr * 64 + m * 16 + lrow) * 32 + kq * 8]);
#pragma unroll
    for (int n = 0; n < 4; ++n)
      bfr[n] = *reinterpret_cast<const bf16x8*>(&Bs[(wc * 64 + n * 16 + lrow) * 32 + kq * 8]);
#pragma unroll
    for (int m = 0; m < 4; ++m)
#pragma unroll
      for (int n = 0; n < 4; ++n)
        acc[m][n] = __builtin_amdgcn_mfma_f32_16x16x32_bf16(af[m], bfr[n], acc[m][n], 0, 0, 0);
    __syncthreads();
  }

#pragma unroll
  for (int m = 0; m < 4; ++m) {
#pragma unroll
    for (int n = 0; n < 4; ++n) {
      const int col = bn + wc * 64 + n * 16 + lrow;
#pragma unroll
      for (int r = 0; r < 4; ++r) {
        const int row = bm + wr * 64 + m * 16 + kq * 4 + r;
        const float xv = acc[m][n][r] + aux[col];
        const float sp = fmaxf(xv, 0.f) + log1pf(__expf(-fabsf(xv)));
        outB[(size_t)row * N + col] = f2bf(sp);
      }
    }
  }
}

// ---------------- x_proj GEMM, split-K over 8 parts of 256 ----------------
__global__ __launch_bounds__(256) void gemm_xproj_splitk(const u16* __restrict__ A,
                                                         const u16* __restrict__ Bw,
                                                         float* __restrict__ p0,
                                                         float* __restrict__ p1) {
  __shared__ __align__(16) u16 As[128 * 32];
  __shared__ __align__(16) u16 Bs[128 * 32];
  const int tid = threadIdx.x;
  const int lane = tid & 63;
  const int wid = tid >> 6;
  const int wr = wid >> 1, wc = wid & 1;
  const int kp = blockIdx.x;
  const int bm = blockIdx.y * 128;
  const int koff = kp * 256;
  const int r0 = tid >> 2;
  const int c0 = (tid & 3) * 8;
  const int lrow = lane & 15, kq = lane >> 4;

  f32x4 acc[4][4] = {};
  const u16* Ab = A + (size_t)bm * DI + koff;
  const u16* Bb = Bw + koff;

  for (int k0 = 0; k0 < 256; k0 += 32) {
    gload16(Ab + (size_t)r0 * DI + k0 + c0, &As[r0 * 32 + c0]);
    gload16(Ab + (size_t)(r0 + 64) * DI + k0 + c0, &As[(r0 + 64) * 32 + c0]);
    gload16(Bb + (size_t)r0 * DI + k0 + c0, &Bs[r0 * 32 + c0]);
    gload16(Bb + (size_t)(r0 + 64) * DI + k0 + c0, &Bs[(r0 + 64) * 32 + c0]);
    __syncthreads();
    bf16x8 af[4], bfr[4];
#pragma unroll
    for (int m = 0; m < 4; ++m)
      af[m] = *reinterpret_cast<const bf16x8*>(&As[(wr * 64 + m * 16 + lrow) * 32 + kq * 8]);
#pragma unroll
    for (int n = 0; n < 4; ++n)
      bfr[n] = *reinterpret_cast<const bf16x8*>(&Bs[(wc * 64 + n * 16 + lrow) * 32 + kq * 8]);
#pragma unroll
    for (int m = 0; m < 4; ++m)
#pragma unroll
      for (int n = 0; n < 4; ++n)
        acc[m][n] = __builtin_amdgcn_mfma_f32_16x16x32_bf16(af[m], bfr[n], acc[m][n], 0, 0, 0);
    __syncthreads();
  }

  float* dst = (kp < 4 ? p0 : p1) + (size_t)(kp & 3) * MR * 128;
#pragma unroll
  for (int m = 0; m < 4; ++m)
#pragma unroll
    for (int n = 0; n < 4; ++n) {
      const int col = wc * 64 + n * 16 + lrow;
#pragma unroll
      for (int r = 0; r < 4; ++r) {
        const int row = bm + wr * 64 + m * 16 + kq * 4 + r;
        dst[(size_t)row * 128 + col] = acc[m][n][r];
      }
    }
}

// reduce 8 partial slices -> xdbl f32 (col<96) + dtr bf16 (col<64)
__global__ __launch_bounds__(256) void xproj_reduce(const float* __restrict__ p0,
                                                    const float* __restrict__ p1,
                                                    float* __restrict__ xdbl,
                                                    u16* __restrict__ dtr) {
  const int id = blockIdx.x * 256 + threadIdx.x;  // 4096*128
  const int row = id >> 7, col = id & 127;
  float s = 0.f;
#pragma unroll
  for (int kp = 0; kp < 4; ++kp) s += p0[(size_t)kp * MR * 128 + id];
#pragma unroll
  for (int kp = 0; kp < 4; ++kp) s += p1[(size_t)kp * MR * 128 + id];
  if (col < 96) xdbl[(size_t)row * 96 + col] = s;
  if (col < 64) dtr[(size_t)row * 64 + col] = f2bf(s);
}

// ---------------- depthwise causal conv1d + silu, 8 channels/thread ----------------
__global__ __launch_bounds__(256) void conv_silu_kernel(const u16* __restrict__ xz,
                                                        const float* __restrict__ Wc,
                                                        const float* __restrict__ bc,
                                                        u16* __restrict__ uc) {
  const int id = blockIdx.x * 256 + threadIdx.x;  // B*LS*DI/8 = 2^20
  const int d8 = id & (DI / 8 - 1);
  const int t = (id >> 8) & (LS - 1);
  const int b = id >> 19;
  const int d0 = d8 * 8;
  const size_t rowb = (size_t)b * LS;
  bf16x8 r[4];
#pragma unroll
  for (int k = 0; k < 4; ++k) {
    const int tt = t - 3 + k;
    if (tt >= 0)
      r[k] = *reinterpret_cast<const bf16x8*>(&xz[(rowb + tt) * (2 * DI) + d0]);
    else
      r[k] = bf16x8{0, 0, 0, 0, 0, 0, 0, 0};
  }
  const float4 bc0 = *reinterpret_cast<const float4*>(&bc[d0]);
  const float4 bc1 = *reinterpret_cast<const float4*>(&bc[d0 + 4]);
  const float bcv[8] = {bc0.x, bc0.y, bc0.z, bc0.w, bc1.x, bc1.y, bc1.z, bc1.w};
  u16 o[8];
#pragma unroll
  for (int j = 0; j < 8; ++j) {
    const float4 w = *reinterpret_cast<const float4*>(&Wc[(d0 + j) * 4]);
    float s = bcv[j];
    s += bf2f((u16)r[0][j]) * w.x;
    s += bf2f((u16)r[1][j]) * w.y;
    s += bf2f((u16)r[2][j]) * w.z;
    s += bf2f((u16)r[3][j]) * w.w;
    const float sl = s / (1.f + __expf(-s));
    o[j] = f2bf(sl);
  }
  *reinterpret_cast<bf16x8*>(&uc[(rowb + t) * DI + d0]) =
      *reinterpret_cast<const bf16x8*>(o);
}

// ---------------- chunked selective scan ----------------
// NCH=64 chunks of CL=32; windows of 16 t. 128-thread blocks over 128 channels.
// Grid 2048: d0 = (blk&15)*128, c = (blk>>4)&63, b = blk>>10.
// Fast path: A[j] == -(j+1) (S4D-real init) -> dA[j] = e^(j+1), e = exp2(-dt*L2E).
// P is never materialized: P = exp(A*sum_dt); phase1 stores sum_dt (1MB), phase2 recomputes.

// Phase 1: local scan from h=0; emit S (final local state) and sdt = sum_dt.
__global__ __launch_bounds__(128, 4) void scan_phase1(const u16* __restrict__ dtb,
                                                      const float* __restrict__ xdbl,
                                                      const u16* __restrict__ uc,
                                                      const float* __restrict__ Alog,
                                                      float* __restrict__ sdtb,
                                                      float* __restrict__ S) {
  __shared__ __align__(16) u16 s_dt[16 * 128];   // 4KB
  __shared__ __align__(16) u16 s_uc[16 * 128];   // 4KB
  __shared__ __align__(16) float s_b[16 * 16];   // 1KB
  const int tid = threadIdx.x;
  const int blk = blockIdx.x;
  const int d0 = (blk & 15) * 128;
  const int c = (blk >> 4) & (NCH - 1);
  const int b = blk >> 10;
  const int d = d0 + tid;
  const size_t tbase = (size_t)b * LS + c * CL;

  float Av[16];
  bool fastA = true;
#pragma unroll
  for (int j = 0; j < 16; j += 4) {
    const float4 Alv = *reinterpret_cast<const float4*>(&Alog[d * DSn + j]);
    Av[j + 0] = -__expf(Alv.x); Av[j + 1] = -__expf(Alv.y);
    Av[j + 2] = -__expf(Alv.z); Av[j + 3] = -__expf(Alv.w);
  }
#pragma unroll
  for (int j = 0; j < 16; ++j)
    fastA = fastA && (fabsf(Av[j] + (float)(j + 1)) < 1e-3f * (float)(j + 1));

  float h[16];
#pragma unroll
  for (int j = 0; j < 16; ++j) h[j] = 0.f;
  float sdt = 0.f;

  for (int w = 0; w < 2; ++w) {
    const size_t twb = tbase + w * 16;
#pragma unroll
    for (int j = 0; j < 2; ++j) {  // dt + uc bf16 [16][128]
      const int k = j * 128 + tid;
      const int row = k >> 4, col = (k & 15) * 8;
      gload16(dtb + (twb + row) * DI + d0 + col, &s_dt[row * 128 + col]);
      gload16(uc + (twb + row) * DI + d0 + col, &s_uc[row * 128 + col]);
    }
    if (tid < 64) {  // B [16][16] f32
      gload16((const u16*)(xdbl + (twb + (tid >> 2)) * 96 + DTRk + (tid & 3) * 4),
              (u16*)&s_b[tid * 4]);
    }
    __syncthreads();
    if (fastA) {
      for (int tr = 0; tr < 16; ++tr) {
        const float dtv = bf2f(s_dt[tr * 128 + tid]);
        const float uv = bf2f(s_uc[tr * 128 + tid]);
        const float du = dtv * uv;
        sdt += dtv;
        float dA[16];
        CALC_POWERS(dA, exp2f(-L2E * dtv));
        float Bf[16];
#pragma unroll
        for (int j = 0; j < 16; j += 4) {
          const float4 Bv = *reinterpret_cast<const float4*>(&s_b[tr * 16 + j]);
          Bf[j] = Bv.x; Bf[j + 1] = Bv.y; Bf[j + 2] = Bv.z; Bf[j + 3] = Bv.w;
        }
#pragma unroll
        for (int j = 0; j < 16; ++j) h[j] = dA[j] * h[j] + du * Bf[j];
      }
    } else {
      for (int tr = 0; tr < 16; ++tr) {
        const float dtv = bf2f(s_dt[tr * 128 + tid]);
        const float uv = bf2f(s_uc[tr * 128 + tid]);
        const float du = dtv * uv;
        sdt += dtv;
        float Bf[16];
#pragma unroll
        for (int j = 0; j < 16; j += 4) {
          const float4 Bv = *reinterpret_cast<const float4*>(&s_b[tr * 16 + j]);
          Bf[j] = Bv.x; Bf[j + 1] = Bv.y; Bf[j + 2] = Bv.z; Bf[j + 3] = Bv.w;
        }
#pragma unroll
        for (int j = 0; j < 16; ++j)
          h[j] = exp2f(dtv * Av[j] * L2E) * h[j] + du * Bf[j];
      }
    }
    __syncthreads();
  }

  const size_t oi = (((size_t)b * NCH + c) * DI + d) * DSn;
#pragma unroll
  for (int j = 0; j < 16; j += 4) {
    float4 Sv = {h[j], h[j + 1], h[j + 2], h[j + 3]};
    *reinterpret_cast<float4*>(&S[oi + j]) = Sv;
  }
  sdtb[((size_t)b * NCH + c) * DI + d] = sdt;
}

// Phase 2: serial compose over chunks; P recomputed from Alog + sdt;
// overwrite S with Hin (state entering each chunk).
__global__ __launch_bounds__(256) void scan_phase2(const float* __restrict__ Alog,
                                                   const float* __restrict__ sdtb,
                                                   float* __restrict__ S) {
  const int gid = blockIdx.x * 256 + threadIdx.x;
  const int ng = gid & 3;
  const int d = (gid >> 2) & (DI - 1);
  const int b = gid >> 13;
  const float4 Alv = *reinterpret_cast<const float4*>(&Alog[d * DSn + ng * 4]);
  const float Av[4] = {-__expf(Alv.x) * L2E, -__expf(Alv.y) * L2E,
                       -__expf(Alv.z) * L2E, -__expf(Alv.w) * L2E};
  float4 h = {0.f, 0.f, 0.f, 0.f};
  for (int cc = 0; cc < NCH; ++cc) {
    const float sdt = sdtb[((size_t)b * NCH + cc) * DI + d];
    float4 Pv;
    Pv.x = exp2f(Av[0] * sdt);
    Pv.y = exp2f(Av[1] * sdt);
    Pv.z = exp2f(Av[2] * sdt);
    Pv.w = exp2f(Av[3] * sdt);
    const size_t oi = (((size_t)b * NCH + cc) * DI + d) * DSn + ng * 4;
    const float4 Sv = *reinterpret_cast<const float4*>(&S[oi]);
    *reinterpret_cast<float4*>(&S[oi]) = h;
    h.x = Sv.x + Pv.x * h.x;
    h.y = Sv.y + Pv.y * h.y;
    h.z = Sv.z + Pv.z * h.z;
    h.w = Sv.w + Pv.w * h.w;
  }
}

// Phase 3: h = Hin; re-scan chunk computing y, +D*u, gate silu(z), store bf16 y.
__global__ __launch_bounds__(128, 4) void scan_phase3(const u16* __restrict__ dtb,
                                                      const float* __restrict__ xdbl,
                                                      const u16* __restrict__ uc,
                                                      const u16* __restrict__ xz,
                                                      const float* __restrict__ Alog,
                                                      const float* __restrict__ Dp,
                                                      const float* __restrict__ Hin,
                                                      u16* __restrict__ yb) {
  __shared__ __align__(16) u16 s_dt[16 * 128];   // 4KB
  __shared__ __align__(16) u16 s_uc[16 * 128];   // 4KB
  __shared__ __align__(16) u16 s_z[16 * 128];    // 4KB
  __shared__ __align__(16) float s_bc[16 * 32];  // 2KB
  const int tid = threadIdx.x;
  const int blk = blockIdx.x;
  const int d0 = (blk & 15) * 128;
  const int c = (blk >> 4) & (NCH - 1);
  const int b = blk >> 10;
  const int d = d0 + tid;
  const size_t tbase = (size_t)b * LS + c * CL;

  float Av[16];
  bool fastA = true;
#pragma unroll
  for (int j = 0; j < 16; j += 4) {
    const float4 Alv = *reinterpret_cast<const float4*>(&Alog[d * DSn + j]);
    Av[j + 0] = -__expf(Alv.x); Av[j + 1] = -__expf(Alv.y);
    Av[j + 2] = -__expf(Alv.z); Av[j + 3] = -__expf(Alv.w);
  }
#pragma unroll
  for (int j = 0; j < 16; ++j)
    fastA = fastA && (fabsf(Av[j] + (float)(j + 1)) < 1e-3f * (float)(j + 1));

  const float Dd = Dp[d];
  const size_t oi = (((size_t)b * NCH + c) * DI + d) * DSn;
  float h[16];
#pragma unroll
  for (int j = 0; j < 16; j += 4) {
    const float4 hv = *reinterpret_cast<const float4*>(&Hin[oi + j]);
    h[j] = hv.x; h[j + 1] = hv.y; h[j + 2] = hv.z; h[j + 3] = hv.w;
  }

  for (int w = 0; w < 2; ++w) {
    const size_t twb = tbase + w * 16;
#pragma unroll
    for (int j = 0; j < 2; ++j) {  // dt, uc, z bf16 [16][128]
      const int k = j * 128 + tid;
      const int row = k >> 4, col = (k & 15) * 8;
      gload16(dtb + (twb + row) * DI + d0 + col, &s_dt[row * 128 + col]);
      gload16(uc + (twb + row) * DI + d0 + col, &s_uc[row * 128 + col]);
      gload16(xz + (twb + row) * (2 * DI) + DI + d0 + col, &s_z[row * 128 + col]);
    }
    {  // B|C [16][32] f32, all 128 threads
      gload16((const u16*)(xdbl + (twb + (tid >> 3)) * 96 + DTRk + (tid & 7) * 4),
              (u16*)&s_bc[tid * 4]);
    }
    __syncthreads();
#define P3_STEP(DA_STMT)                                                        \
    for (int tr = 0; tr < 16; ++tr) {                                           \
      const float dtv = bf2f(s_dt[tr * 128 + tid]);                             \
      const float uv = bf2f(s_uc[tr * 128 + tid]);                              \
      const float du = dtv * uv;                                                \
      float dA[16];                                                             \
      DA_STMT;                                                                  \
      float Bf[16], Cf[16];                                                     \
      _Pragma("unroll")                                                         \
      for (int j = 0; j < 16; j += 4) {                                         \
        const float4 Bv = *reinterpret_cast<const float4*>(&s_bc[tr * 32 + j]); \
        const float4 Cv = *reinterpret_cast<const float4*>(&s_bc[tr * 32 + 16 + j]); \
        Bf[j] = Bv.x; Bf[j + 1] = Bv.y; Bf[j + 2] = Bv.z; Bf[j + 3] = Bv.w;     \
        Cf[j] = Cv.x; Cf[j + 1] = Cv.y; Cf[j + 2] = Cv.z; Cf[j + 3] = Cv.w;     \
      }                                                                         \
      _Pragma("unroll")                                                         \
      for (int j = 0; j < 16; ++j) h[j] = dA[j] * h[j] + du * Bf[j];            \
      float y0 = 0.f, y1 = 0.f, y2 = 0.f, y3 = 0.f;                             \
      _Pragma("unroll")                                                         \
      for (int j = 0; j < 16; j += 4) {                                         \
        y0 += h[j] * Cf[j];                                                     \
        y1 += h[j + 1] * Cf[j + 1];                                             \
        y2 += h[j + 2] * Cf[j + 2];                                             \
        y3 += h[j + 3] * Cf[j + 3];                                             \
      }                                                                         \
      const float y = (y0 + y1) + (y2 + y3) + uv * Dd;                          \
      const float z = bf2f(s_z[tr * 128 + tid]);                                \
      const float sz = z / (1.f + __expf(-z));                                  \
      yb[(twb + tr) * DI + d] = f2bf(y * sz);                                   \
    }
    if (fastA) {
      P3_STEP(CALC_POWERS(dA, exp2f(-L2E * dtv)));
    } else {
      P3_STEP({ _Pragma("unroll") for (int j = 0; j < 16; ++j) dA[j] = exp2f(dtv * Av[j] * L2E); });
    }
#undef P3_STEP
    __syncthreads();
  }
}

extern "C" void kernel_launch(void* const* d_in, const int* in_sizes, int n_in,
                              void* d_out, int out_size, void* d_ws, size_t ws_size,
                              hipStream_t stream) {
  (void)in_sizes; (void)n_in; (void)out_size; (void)ws_size;
  const float* x      = (const float*)d_in[0];
  const float* norm_w = (const float*)d_in[1];
  const float* W_in   = (const float*)d_in[2];
  const float* W_conv = (const float*)d_in[3];
  const float* b_conv = (const float*)d_in[4];
  const float* W_xp   = (const float*)d_in[5];
  const float* W_dt   = (const float*)d_in[6];
  const float* b_dt   = (const float*)d_in[7];
  const float* A_log  = (const float*)d_in[8];
  const float* Dvec   = (const float*)d_in[9];
  const float* W_out  = (const float*)d_in[10];
  float* out = (float*)d_out;

  char* ws = (char*)d_ws;
  size_t off = 0;
  auto alloc = [&](size_t bytes) -> void* {
    void* p = ws + off;
    off += (bytes + 255) & ~(size_t)255;
    return p;
  };
  u16* Win_b  = (u16*)alloc((size_t)4096 * 1024 * 2);   // 8 MB (dead after in_proj)
  u16* Wout_b = (u16*)alloc((size_t)1024 * 2048 * 2);
  u16* Wxp_b  = (u16*)alloc((size_t)128 * 2048 * 2);
  u16* Wdt_b  = (u16*)alloc((size_t)2048 * 64 * 2);
  u16* xn_b   = (u16*)alloc((size_t)MR * DM * 2);       // 8 MB (dead after in_proj)
  u16* xz_b   = (u16*)alloc((size_t)MR * 2 * DI * 2);   // 32 MB
  u16* uc_b   = (u16*)alloc((size_t)MR * DI * 2);       // 16 MB
  float* xdbl = (float*)alloc((size_t)MR * 96 * 4);     // 1.5 MB
  u16* dtr_b  = (u16*)alloc((size_t)MR * 64 * 2);       // 0.5 MB
  u16* dtf_b  = (u16*)alloc((size_t)MR * DI * 2);       // 16 MB
  u16* y_b    = (u16*)alloc((size_t)MR * DI * 2);       // 16 MB; sdt aliases (dead before y write)
  float* Sbuf = (float*)alloc((size_t)2 * NCH * DI * DSn * 4);  // 16 MB
  float* part0 = (float*)Win_b;
  float* part1 = (float*)xn_b;
  float* sdtb = (float*)y_b;   // 1 MB; consumed by phase2 before phase3 writes y
  // out_proj partials: 4 x 8MB bf16 = 32MB, alias xz_b (dead after scan_phase3).
  u16* opart = (u16*)xz_b;

  // fused rmsnorm + weight converts (float4-wide)
  cvt_norm<<<MR, 256, 0, stream>>>(x, norm_w, W_in, W_out, W_dt, W_xp,
                                   xn_b, Win_b, Wout_b, Wdt_b, Wxp_b);

  // xz = xn @ W_in^T : [4096,4096] -- 128x256 tiles, 16x16x32 MFMA, 2 blocks/CU
  gemm128n256<0><<<dim3(16, 32, 1), 512, 0, stream>>>(xn_b, Win_b, MR, 4096, 1024, 1024,
                                                      xz_b);
  // depthwise conv + silu -> u_conv (8 ch/thread)
  conv_silu_kernel<<<4096, 256, 0, stream>>>(xz_b, W_conv, b_conv, uc_b);
  // x_dbl = u_conv @ W_xproj^T : [4096,96] via split-K(8) + reduce
  gemm_xproj_splitk<<<dim3(8, 32), 256, 0, stream>>>(uc_b, Wxp_b, part0, part1);
  xproj_reduce<<<2048, 256, 0, stream>>>(part0, part1, xdbl, dtr_b);
  // dt = softplus(dtr @ W_dt^T + b_dt) : [4096,2048] bf16
  gemm_dt<<<dim3(16, 32), 256, 0, stream>>>(dtr_b, Wdt_b, MR, 2048, 64, dtf_b, b_dt);
  // chunked selective scan: local scans -> compose (S:=Hin) -> rescan+gate
  scan_phase1<<<2048, 128, 0, stream>>>(dtf_b, xdbl, uc_b, A_log, sdtb, Sbuf);
  scan_phase2<<<64, 256, 0, stream>>>(A_log, sdtb, Sbuf);
  scan_phase3<<<2048, 128, 0, stream>>>(dtf_b, xdbl, uc_b, xz_b, A_log, Dvec,
                                        Sbuf, y_b);
  // out = y @ W_out^T + x : split-K=4 (512 blocks = 2/CU), bf16 partials + reduce
  gemm128n256<1><<<dim3(4, 32, 4), 512, 0, stream>>>(y_b, Wout_b, MR, 1024, 2048, 512,
                                                     opart);
  outproj_reduce4b<<<2048, 256, 0, stream>>>(opart, x, out);
}

// Round 19
// 212.968 us; speedup vs baseline: 1.0189x; 1.0189x over previous
//
#include <hip/hip_runtime.h>

typedef unsigned short u16;
typedef unsigned int u32;
typedef short bf16x8 __attribute__((ext_vector_type(8)));
typedef float f32x4 __attribute__((ext_vector_type(4)));

static constexpr int LS = 2048;   // seq len
static constexpr int DM = 1024;   // d_model
static constexpr int DI = 2048;   // d_inner
static constexpr int DSn = 16;    // d_state
static constexpr int DTRk = 64;   // dt_rank
static constexpr int MR = 4096;   // B*L rows
static constexpr int NCH = 64;    // scan chunks
static constexpr int CL = LS / NCH;  // 32 timesteps per chunk
static constexpr float L2E = 1.44269504f;

#define DEV __device__ __forceinline__

DEV u16 f2bf(float f) {
  u32 u = __float_as_uint(f);
  u32 r = (u + 0x7FFF + ((u >> 16) & 1)) >> 16;
  return (u16)r;
}
DEV float bf2f(u16 h) { return __uint_as_float(((u32)h) << 16); }

DEV void gload16(const u16* g, u16* l) {
  __builtin_amdgcn_global_load_lds((const __attribute__((address_space(1))) u32*)g,
                                   (__attribute__((address_space(3))) u32*)l, 16, 0, 0);
}

DEV void bar() { asm volatile("s_barrier" ::: "memory"); }

// powers tree: dst[j] = base^(j+1), depth 4, 15 muls
#define CALC_POWERS(dst, basev)                                              \
  do {                                                                       \
    const float e1_ = (basev);                                               \
    const float e2_ = e1_ * e1_, e3_ = e2_ * e1_, e4_ = e2_ * e2_;           \
    const float e5_ = e4_ * e1_, e6_ = e4_ * e2_, e7_ = e4_ * e3_,           \
                e8_ = e4_ * e4_;                                             \
    dst[0] = e1_; dst[1] = e2_; dst[2] = e3_; dst[3] = e4_;                  \
    dst[4] = e5_; dst[5] = e6_; dst[6] = e7_; dst[7] = e8_;                  \
    dst[8] = e8_ * e1_;  dst[9] = e8_ * e2_;  dst[10] = e8_ * e3_;           \
    dst[11] = e8_ * e4_; dst[12] = e8_ * e5_; dst[13] = e8_ * e6_;           \
    dst[14] = e8_ * e7_; dst[15] = e8_ * e8_;                                \
  } while (0)

// ---------------- fused RMSNorm (1 row/block) + weight converts (float4-wide) ----------------
__global__ __launch_bounds__(256) void cvt_norm(const float* __restrict__ x,
                                                const float* __restrict__ w,
                                                const float* __restrict__ W_in,
                                                const float* __restrict__ W_out,
                                                const float* __restrict__ W_dt,
                                                const float* __restrict__ W_xp,
                                                u16* __restrict__ xn,
                                                u16* __restrict__ Win_b,
                                                u16* __restrict__ Wout_b,
                                                u16* __restrict__ Wdt_b,
                                                u16* __restrict__ Wxp_b) {
  const int row = blockIdx.x;
  const int tid = threadIdx.x;
  {  // rmsnorm of row
    const float4 v = reinterpret_cast<const float4*>(x + (size_t)row * DM)[tid];
    float ss = v.x * v.x + v.y * v.y + v.z * v.z + v.w * v.w;
#pragma unroll
    for (int o = 32; o; o >>= 1) ss += __shfl_xor(ss, o);
    __shared__ float red[4];
    if ((tid & 63) == 0) red[tid >> 6] = ss;
    __syncthreads();
    const float tot = red[0] + red[1] + red[2] + red[3];
    const float scale = rsqrtf(tot * (1.0f / DM) + 1e-5f);
    const float4 wv = reinterpret_cast<const float4*>(w)[tid];
    ushort4 o4;
    o4.x = f2bf(v.x * scale * wv.x);
    o4.y = f2bf(v.y * scale * wv.y);
    o4.z = f2bf(v.z * scale * wv.z);
    o4.w = f2bf(v.w * scale * wv.w);
    *reinterpret_cast<ushort4*>(&xn[(size_t)row * DM + tid * 4]) = o4;
  }
  // weight converts, float4-wide grid-stride (all boundaries divisible by 4)
  const int Q0 = (4096 * 1024) / 4;
  const int Q1 = Q0 + (1024 * 2048) / 4;
  const int Q2 = Q1 + (2048 * 64) / 4;
  const int Q3 = Q2 + (128 * 2048) / 4;
  int q = blockIdx.x * 256 + tid;
  const int stride = gridDim.x * 256;
  for (; q < Q3; q += stride) {
    float4 v;
    u16* dst;
    int jj;
    if (q < Q0) {
      jj = q * 4;
      v = reinterpret_cast<const float4*>(W_in)[q];
      dst = Win_b + jj;
    } else if (q < Q1) {
      jj = (q - Q0) * 4;
      v = reinterpret_cast<const float4*>(W_out)[q - Q0];
      dst = Wout_b + jj;
    } else if (q < Q2) {
      jj = (q - Q1) * 4;
      v = reinterpret_cast<const float4*>(W_dt)[q - Q1];
      dst = Wdt_b + jj;
    } else {
      jj = (q - Q2) * 4;
      const int r = jj >> 11;
      if (r < 96) {
        v = reinterpret_cast<const float4*>(W_xp)[(r * 2048 + (jj & 2047)) / 4];
      } else {
        v = float4{0.f, 0.f, 0.f, 0.f};
      }
      dst = Wxp_b + jj;
    }
    ushort4 o4;
    o4.x = f2bf(v.x); o4.y = f2bf(v.y); o4.z = f2bf(v.z); o4.w = f2bf(v.w);
    *reinterpret_cast<ushort4*>(dst) = o4;
  }
}

// ================= 128x256 GEMM, BK=32, 16x16x32 MFMA, 2 blocks/CU =================
// 8 waves of 64x64 (2M x 4N). LDS: 2 superbuffers x 24KB = 48KB -> 2 blocks/CU.
// 1 barrier per K-tile. Swizzle slot = kq ^ ((row>>1)&3), inverse on global source.
// EPI 0: bf16 out at outB. EPI 1: bf16 partial at outB + z*MR*N (split-K over blockIdx.z).
template <int EPI>
__global__ __launch_bounds__(512, 4) void gemm128n256(const u16* __restrict__ A,
                                                      const u16* __restrict__ Bw,
                                                      int M, int N, int K, int Klen,
                                                      u16* __restrict__ outB) {
  __shared__ __align__(16) u16 SL[2 * 12288];  // 48 KB; super = A[0,4096) B[4096,12288) u16
  const int tid = threadIdx.x;
  const int lane = tid & 63;
  const int wid = tid >> 6;
  const int wr = wid >> 2;   // 0..1 (M half)
  const int wc = wid & 3;    // 0..3 (N quarter)
  const int lrow = lane & 15;
  const int kq = lane >> 4;  // 0..3

  const int nwg = gridDim.x * gridDim.y;
  int wg = blockIdx.y * gridDim.x + blockIdx.x;
  wg = (wg & 7) * (nwg >> 3) + (wg >> 3);
  const int bn = (wg % gridDim.x) * 256;
  const int bm = (wg / gridDim.x) * 128;
  const int koff = blockIdx.z * Klen;

  const int nt = Klen >> 5;  // BK=32

  f32x4 acc[4][4] = {};
  bf16x8 a[4], b[4];

  // staging indices (linear LDS dest, inverse-swizzled source)
  const int srA = tid >> 2;                       // A row 0..127
  const int slA = (tid & 3) ^ ((srA >> 1) & 3);   // source slot
  const int srB0 = tid >> 2, srB1 = 128 + (tid >> 2);  // B rows
  const int slB0 = (tid & 3) ^ ((srB0 >> 1) & 3);
  const int slB1 = (tid & 3) ^ ((srB1 >> 1) & 3);

#define STAGE_TILE(ktile, sup)                                                          \
  do {                                                                                  \
    const int k0_ = koff + (ktile) * 32;                                                \
    gload16(A + (size_t)(bm + srA) * K + k0_ + slA * 8, &SL[(sup) + tid * 8]);          \
    gload16(Bw + (size_t)(bn + srB0) * K + k0_ + slB0 * 8, &SL[(sup) + 4096 + tid * 8]);\
    gload16(Bw + (size_t)(bn + srB1) * K + k0_ + slB1 * 8, &SL[(sup) + 8192 + tid * 8]);\
  } while (0)

  // prologue: stage tile0 -> super0, publish
  STAGE_TILE(0, 0);
  asm volatile("s_waitcnt vmcnt(0)" ::: "memory");
  bar();

  for (int t = 0; t < nt; ++t) {
    const int cs = (t & 1) * 12288;
    const int ns = ((t + 1) & 1) * 12288;
    if (t + 1 < nt) STAGE_TILE(t + 1, ns);
    // fragment reads (swizzled) + 16 MFMA; compiler free to pipeline
#pragma unroll
    for (int m = 0; m < 4; ++m) {
      const int row = wr * 64 + m * 16 + lrow;
      a[m] = *reinterpret_cast<const bf16x8*>(
          &SL[cs + row * 32 + (kq ^ ((row >> 1) & 3)) * 8]);
    }
#pragma unroll
    for (int n = 0; n < 4; ++n) {
      const int row = wc * 64 + n * 16 + lrow;
      b[n] = *reinterpret_cast<const bf16x8*>(
          &SL[cs + 4096 + row * 32 + (kq ^ ((row >> 1) & 3)) * 8]);
    }
    __builtin_amdgcn_s_setprio(1);
#pragma unroll
    for (int m = 0; m < 4; ++m)
#pragma unroll
      for (int n = 0; n < 4; ++n)
        acc[m][n] = __builtin_amdgcn_mfma_f32_16x16x32_bf16(a[m], b[n], acc[m][n], 0, 0, 0);
    __builtin_amdgcn_s_setprio(0);
    if (t + 1 < nt) {
      asm volatile("s_waitcnt vmcnt(0)" ::: "memory");  // next tile landed
      bar();                                            // publish; reads of cs retired
    }
  }
#undef STAGE_TILE

  u16* dstB = (EPI == 0) ? outB : outB + (size_t)blockIdx.z * MR * N;
#pragma unroll
  for (int m = 0; m < 4; ++m)
#pragma unroll
    for (int n = 0; n < 4; ++n) {
      const int col = bn + wc * 64 + n * 16 + lrow;
#pragma unroll
      for (int rr = 0; rr < 4; ++rr) {
        const int row = bm + wr * 64 + m * 16 + kq * 4 + rr;
        dstB[(size_t)row * N + col] = f2bf(acc[m][n][rr]);
      }
    }
}

// out = bf16 p0 + bf16 p1 + x (8-wide); p slices are MR*1024 bf16 each
__global__ __launch_bounds__(256) void outproj_reduce2(const u16* __restrict__ p,
                                                       const float* __restrict__ x,
                                                       float* __restrict__ out) {
  const int id = blockIdx.x * 256 + threadIdx.x;  // over 4096*1024/8
  const bf16x8 a = *reinterpret_cast<const bf16x8*>(&p[(size_t)id * 8]);
  const bf16x8 b = *reinterpret_cast<const bf16x8*>(&p[(size_t)MR * 1024 + (size_t)id * 8]);
  const float4 x0 = reinterpret_cast<const float4*>(x)[id * 2];
  const float4 x1 = reinterpret_cast<const float4*>(x)[id * 2 + 1];
  float4 o0, o1;
  o0.x = x0.x + bf2f((u16)a[0]) + bf2f((u16)b[0]);
  o0.y = x0.y + bf2f((u16)a[1]) + bf2f((u16)b[1]);
  o0.z = x0.z + bf2f((u16)a[2]) + bf2f((u16)b[2]);
  o0.w = x0.w + bf2f((u16)a[3]) + bf2f((u16)b[3]);
  o1.x = x1.x + bf2f((u16)a[4]) + bf2f((u16)b[4]);
  o1.y = x1.y + bf2f((u16)a[5]) + bf2f((u16)b[5]);
  o1.z = x1.z + bf2f((u16)a[6]) + bf2f((u16)b[6]);
  o1.w = x1.w + bf2f((u16)a[7]) + bf2f((u16)b[7]);
  reinterpret_cast<float4*>(out)[id * 2] = o0;
  reinterpret_cast<float4*>(out)[id * 2 + 1] = o1;
}

// ---------------- MFMA GEMM 128^2 (m97 structure), dt-proj epilogue ----------------
__global__ __launch_bounds__(256) void gemm_dt(const u16* __restrict__ A,
                                               const u16* __restrict__ Bw,
                                               int M, int N, int K,
                                               u16* __restrict__ outB,
                                               const float* __restrict__ aux) {
  __shared__ __align__(16) u16 As[128 * 32];
  __shared__ __align__(16) u16 Bs[128 * 32];
  const int tid = threadIdx.x;
  const int lane = tid & 63;
  const int wid = tid >> 6;
  const int wr = wid >> 1, wc = wid & 1;
  const int nwg = gridDim.x * gridDim.y;
  int wg = blockIdx.y * gridDim.x + blockIdx.x;
  wg = (wg & 7) * (nwg >> 3) + (wg >> 3);
  const int bn = (wg % gridDim.x) * 128;
  const int bm = (wg / gridDim.x) * 128;
  const int r0 = tid >> 2;
  const int c0 = (tid & 3) * 8;
  const int lrow = lane & 15, kq = lane >> 4;

  f32x4 acc[4][4] = {};

  const u16* Ab = A + (size_t)bm * K;
  const u16* Bb = Bw + (size_t)bn * K;

  for (int k0 = 0; k0 < K; k0 += 32) {
    gload16(Ab + (size_t)r0 * K + k0 + c0, &As[r0 * 32 + c0]);
    gload16(Ab + (size_t)(r0 + 64) * K + k0 + c0, &As[(r0 + 64) * 32 + c0]);
    gload16(Bb + (size_t)r0 * K + k0 + c0, &Bs[r0 * 32 + c0]);
    gload16(Bb + (size_t)(r0 + 64) * K + k0 + c0, &Bs[(r0 + 64) * 32 + c0]);
    __syncthreads();
    bf16x8 af[4], bfr[4];
#pragma unroll
    for (int m = 0; m < 4; ++m)
      af[m] = *reinterpret_cast<const bf16x8*>(&As[(wr * 64 + m * 16 + lrow) * 32 + kq * 8]);
#pragma unroll
    for (int n = 0; n < 4; ++n)
      bfr[n] = *reinterpret_cast<const bf16x8*>(&Bs[(wc * 64 + n * 16 + lrow) * 32 + kq * 8]);
#pragma unroll
    for (int m = 0; m < 4; ++m)
#pragma unroll
      for (int n = 0; n < 4; ++n)
        acc[m][n] = __builtin_amdgcn_mfma_f32_16x16x32_bf16(af[m], bfr[n], acc[m][n], 0, 0, 0);
    __syncthreads();
  }

#pragma unroll
  for (int m = 0; m < 4; ++m) {
#pragma unroll
    for (int n = 0; n < 4; ++n) {
      const int col = bn + wc * 64 + n * 16 + lrow;
#pragma unroll
      for (int r = 0; r < 4; ++r) {
        const int row = bm + wr * 64 + m * 16 + kq * 4 + r;
        const float xv = acc[m][n][r] + aux[col];
        const float sp = fmaxf(xv, 0.f) + log1pf(__expf(-fabsf(xv)));
        outB[(size_t)row * N + col] = f2bf(sp);
      }
    }
  }
}

// ---------------- x_proj GEMM, split-K over 8 parts of 256 ----------------
__global__ __launch_bounds__(256) void gemm_xproj_splitk(const u16* __restrict__ A,
                                                         const u16* __restrict__ Bw,
                                                         float* __restrict__ p0,
                                                         float* __restrict__ p1) {
  __shared__ __align__(16) u16 As[128 * 32];
  __shared__ __align__(16) u16 Bs[128 * 32];
  const int tid = threadIdx.x;
  const int lane = tid & 63;
  const int wid = tid >> 6;
  const int wr = wid >> 1, wc = wid & 1;
  const int kp = blockIdx.x;
  const int bm = blockIdx.y * 128;
  const int koff = kp * 256;
  const int r0 = tid >> 2;
  const int c0 = (tid & 3) * 8;
  const int lrow = lane & 15, kq = lane >> 4;

  f32x4 acc[4][4] = {};
  const u16* Ab = A + (size_t)bm * DI + koff;
  const u16* Bb = Bw + koff;

  for (int k0 = 0; k0 < 256; k0 += 32) {
    gload16(Ab + (size_t)r0 * DI + k0 + c0, &As[r0 * 32 + c0]);
    gload16(Ab + (size_t)(r0 + 64) * DI + k0 + c0, &As[(r0 + 64) * 32 + c0]);
    gload16(Bb + (size_t)r0 * DI + k0 + c0, &Bs[r0 * 32 + c0]);
    gload16(Bb + (size_t)(r0 + 64) * DI + k0 + c0, &Bs[(r0 + 64) * 32 + c0]);
    __syncthreads();
    bf16x8 af[4], bfr[4];
#pragma unroll
    for (int m = 0; m < 4; ++m)
      af[m] = *reinterpret_cast<const bf16x8*>(&As[(wr * 64 + m * 16 + lrow) * 32 + kq * 8]);
#pragma unroll
    for (int n = 0; n < 4; ++n)
      bfr[n] = *reinterpret_cast<const bf16x8*>(&Bs[(wc * 64 + n * 16 + lrow) * 32 + kq * 8]);
#pragma unroll
    for (int m = 0; m < 4; ++m)
#pragma unroll
      for (int n = 0; n < 4; ++n)
        acc[m][n] = __builtin_amdgcn_mfma_f32_16x16x32_bf16(af[m], bfr[n], acc[m][n], 0, 0, 0);
    __syncthreads();
  }

  float* dst = (kp < 4 ? p0 : p1) + (size_t)(kp & 3) * MR * 128;
#pragma unroll
  for (int m = 0; m < 4; ++m)
#pragma unroll
    for (int n = 0; n < 4; ++n) {
      const int col = wc * 64 + n * 16 + lrow;
#pragma unroll
      for (int r = 0; r < 4; ++r) {
        const int row = bm + wr * 64 + m * 16 + kq * 4 + r;
        dst[(size_t)row * 128 + col] = acc[m][n][r];
      }
    }
}

// reduce 8 partial slices -> xdbl f32 (col<96) + dtr bf16 (col<64)
__global__ __launch_bounds__(256) void xproj_reduce(const float* __restrict__ p0,
                                                    const float* __restrict__ p1,
                                                    float* __restrict__ xdbl,
                                                    u16* __restrict__ dtr) {
  const int id = blockIdx.x * 256 + threadIdx.x;  // 4096*128
  const int row = id >> 7, col = id & 127;
  float s = 0.f;
#pragma unroll
  for (int kp = 0; kp < 4; ++kp) s += p0[(size_t)kp * MR * 128 + id];
#pragma unroll
  for (int kp = 0; kp < 4; ++kp) s += p1[(size_t)kp * MR * 128 + id];
  if (col < 96) xdbl[(size_t)row * 96 + col] = s;
  if (col < 64) dtr[(size_t)row * 64 + col] = f2bf(s);
}

// ---------------- depthwise causal conv1d + silu, 8 channels/thread ----------------
__global__ __launch_bounds__(256) void conv_silu_kernel(const u16* __restrict__ xz,
                                                        const float* __restrict__ Wc,
                                                        const float* __restrict__ bc,
                                                        u16* __restrict__ uc) {
  const int id = blockIdx.x * 256 + threadIdx.x;  // B*LS*DI/8 = 2^20
  const int d8 = id & (DI / 8 - 1);
  const int t = (id >> 8) & (LS - 1);
  const int b = id >> 19;
  const int d0 = d8 * 8;
  const size_t rowb = (size_t)b * LS;
  bf16x8 r[4];
#pragma unroll
  for (int k = 0; k < 4; ++k) {
    const int tt = t - 3 + k;
    if (tt >= 0)
      r[k] = *reinterpret_cast<const bf16x8*>(&xz[(rowb + tt) * (2 * DI) + d0]);
    else
      r[k] = bf16x8{0, 0, 0, 0, 0, 0, 0, 0};
  }
  const float4 bc0 = *reinterpret_cast<const float4*>(&bc[d0]);
  const float4 bc1 = *reinterpret_cast<const float4*>(&bc[d0 + 4]);
  const float bcv[8] = {bc0.x, bc0.y, bc0.z, bc0.w, bc1.x, bc1.y, bc1.z, bc1.w};
  u16 o[8];
#pragma unroll
  for (int j = 0; j < 8; ++j) {
    const float4 w = *reinterpret_cast<const float4*>(&Wc[(d0 + j) * 4]);
    float s = bcv[j];
    s += bf2f((u16)r[0][j]) * w.x;
    s += bf2f((u16)r[1][j]) * w.y;
    s += bf2f((u16)r[2][j]) * w.z;
    s += bf2f((u16)r[3][j]) * w.w;
    const float sl = s / (1.f + __expf(-s));
    o[j] = f2bf(sl);
  }
  *reinterpret_cast<bf16x8*>(&uc[(rowb + t) * DI + d0]) =
      *reinterpret_cast<const bf16x8*>(o);
}

// ---------------- chunked selective scan ----------------
// NCH=64 chunks of CL=32; windows of 16 t. 128-thread blocks over 128 channels.
// Grid 2048: d0 = (blk&15)*128, c = (blk>>4)&63, b = blk>>10.
// Fast path: A[j] == -(j+1) (S4D-real init) -> dA[j] = e^(j+1), e = exp2(-dt*L2E).
// P is never materialized: P = exp(A*sum_dt); phase1 stores sum_dt (1MB), phase2 recomputes.

// Phase 1: local scan from h=0; emit S (final local state) and sdt = sum_dt.
__global__ __launch_bounds__(128, 4) void scan_phase1(const u16* __restrict__ dtb,
                                                      const float* __restrict__ xdbl,
                                                      const u16* __restrict__ uc,
                                                      const float* __restrict__ Alog,
                                                      float* __restrict__ sdtb,
                                                      float* __restrict__ S) {
  __shared__ __align__(16) u16 s_dt[16 * 128];   // 4KB
  __shared__ __align__(16) u16 s_uc[16 * 128];   // 4KB
  __shared__ __align__(16) float s_b[16 * 16];   // 1KB
  const int tid = threadIdx.x;
  const int blk = blockIdx.x;
  const int d0 = (blk & 15) * 128;
  const int c = (blk >> 4) & (NCH - 1);
  const int b = blk >> 10;
  const int d = d0 + tid;
  const size_t tbase = (size_t)b * LS + c * CL;

  float Av[16];
  bool fastA = true;
#pragma unroll
  for (int j = 0; j < 16; j += 4) {
    const float4 Alv = *reinterpret_cast<const float4*>(&Alog[d * DSn + j]);
    Av[j + 0] = -__expf(Alv.x); Av[j + 1] = -__expf(Alv.y);
    Av[j + 2] = -__expf(Alv.z); Av[j + 3] = -__expf(Alv.w);
  }
#pragma unroll
  for (int j = 0; j < 16; ++j)
    fastA = fastA && (fabsf(Av[j] + (float)(j + 1)) < 1e-3f * (float)(j + 1));

  float h[16];
#pragma unroll
  for (int j = 0; j < 16; ++j) h[j] = 0.f;
  float sdt = 0.f;

  for (int w = 0; w < 2; ++w) {
    const size_t twb = tbase + w * 16;
#pragma unroll
    for (int j = 0; j < 2; ++j) {  // dt + uc bf16 [16][128]
      const int k = j * 128 + tid;
      const int row = k >> 4, col = (k & 15) * 8;
      gload16(dtb + (twb + row) * DI + d0 + col, &s_dt[row * 128 + col]);
      gload16(uc + (twb + row) * DI + d0 + col, &s_uc[row * 128 + col]);
    }
    if (tid < 64) {  // B [16][16] f32
      gload16((const u16*)(xdbl + (twb + (tid >> 2)) * 96 + DTRk + (tid & 3) * 4),
              (u16*)&s_b[tid * 4]);
    }
    __syncthreads();
    if (fastA) {
      for (int tr = 0; tr < 16; ++tr) {
        const float dtv = bf2f(s_dt[tr * 128 + tid]);
        const float uv = bf2f(s_uc[tr * 128 + tid]);
        const float du = dtv * uv;
        sdt += dtv;
        float dA[16];
        CALC_POWERS(dA, exp2f(-L2E * dtv));
        float Bf[16];
#pragma unroll
        for (int j = 0; j < 16; j += 4) {
          const float4 Bv = *reinterpret_cast<const float4*>(&s_b[tr * 16 + j]);
          Bf[j] = Bv.x; Bf[j + 1] = Bv.y; Bf[j + 2] = Bv.z; Bf[j + 3] = Bv.w;
        }
#pragma unroll
        for (int j = 0; j < 16; ++j) h[j] = dA[j] * h[j] + du * Bf[j];
      }
    } else {
      for (int tr = 0; tr < 16; ++tr) {
        const float dtv = bf2f(s_dt[tr * 128 + tid]);
        const float uv = bf2f(s_uc[tr * 128 + tid]);
        const float du = dtv * uv;
        sdt += dtv;
        float Bf[16];
#pragma unroll
        for (int j = 0; j < 16; j += 4) {
          const float4 Bv = *reinterpret_cast<const float4*>(&s_b[tr * 16 + j]);
          Bf[j] = Bv.x; Bf[j + 1] = Bv.y; Bf[j + 2] = Bv.z; Bf[j + 3] = Bv.w;
        }
#pragma unroll
        for (int j = 0; j < 16; ++j)
          h[j] = exp2f(dtv * Av[j] * L2E) * h[j] + du * Bf[j];
      }
    }
    __syncthreads();
  }

  const size_t oi = (((size_t)b * NCH + c) * DI + d) * DSn;
#pragma unroll
  for (int j = 0; j < 16; j += 4) {
    float4 Sv = {h[j], h[j + 1], h[j + 2], h[j + 3]};
    *reinterpret_cast<float4*>(&S[oi + j]) = Sv;
  }
  sdtb[((size_t)b * NCH + c) * DI + d] = sdt;
}

// Phase 2: serial compose over chunks; P recomputed from Alog + sdt;
// overwrite S with Hin (state entering each chunk). 128 blocks x 128 threads.
__global__ __launch_bounds__(128) void scan_phase2(const float* __restrict__ Alog,
                                                   const float* __restrict__ sdtb,
                                                   float* __restrict__ S) {
  const int gid = blockIdx.x * 128 + threadIdx.x;
  const int ng = gid & 3;
  const int d = (gid >> 2) & (DI - 1);
  const int b = gid >> 13;
  const float4 Alv = *reinterpret_cast<const float4*>(&Alog[d * DSn + ng * 4]);
  const float Av[4] = {-__expf(Alv.x) * L2E, -__expf(Alv.y) * L2E,
                       -__expf(Alv.z) * L2E, -__expf(Alv.w) * L2E};
  float4 h = {0.f, 0.f, 0.f, 0.f};
  for (int cc = 0; cc < NCH; ++cc) {
    const float sdt = sdtb[((size_t)b * NCH + cc) * DI + d];
    float4 Pv;
    Pv.x = exp2f(Av[0] * sdt);
    Pv.y = exp2f(Av[1] * sdt);
    Pv.z = exp2f(Av[2] * sdt);
    Pv.w = exp2f(Av[3] * sdt);
    const size_t oi = (((size_t)b * NCH + cc) * DI + d) * DSn + ng * 4;
    const float4 Sv = *reinterpret_cast<const float4*>(&S[oi]);
    *reinterpret_cast<float4*>(&S[oi]) = h;
    h.x = Sv.x + Pv.x * h.x;
    h.y = Sv.y + Pv.y * h.y;
    h.z = Sv.z + Pv.z * h.z;
    h.w = Sv.w + Pv.w * h.w;
  }
}

// Phase 3: h = Hin; re-scan chunk computing y, +D*u, gate silu(z), store bf16 y.
__global__ __launch_bounds__(128, 4) void scan_phase3(const u16* __restrict__ dtb,
                                                      const float* __restrict__ xdbl,
                                                      const u16* __restrict__ uc,
                                                      const u16* __restrict__ xz,
                                                      const float* __restrict__ Alog,
                                                      const float* __restrict__ Dp,
                                                      const float* __restrict__ Hin,
                                                      u16* __restrict__ yb) {
  __shared__ __align__(16) u16 s_dt[16 * 128];   // 4KB
  __shared__ __align__(16) u16 s_uc[16 * 128];   // 4KB
  __shared__ __align__(16) u16 s_z[16 * 128];    // 4KB
  __shared__ __align__(16) float s_bc[16 * 32];  // 2KB
  const int tid = threadIdx.x;
  const int blk = blockIdx.x;
  const int d0 = (blk & 15) * 128;
  const int c = (blk >> 4) & (NCH - 1);
  const int b = blk >> 10;
  const int d = d0 + tid;
  const size_t tbase = (size_t)b * LS + c * CL;

  float Av[16];
  bool fastA = true;
#pragma unroll
  for (int j = 0; j < 16; j += 4) {
    const float4 Alv = *reinterpret_cast<const float4*>(&Alog[d * DSn + j]);
    Av[j + 0] = -__expf(Alv.x); Av[j + 1] = -__expf(Alv.y);
    Av[j + 2] = -__expf(Alv.z); Av[j + 3] = -__expf(Alv.w);
  }
#pragma unroll
  for (int j = 0; j < 16; ++j)
    fastA = fastA && (fabsf(Av[j] + (float)(j + 1)) < 1e-3f * (float)(j + 1));

  const float Dd = Dp[d];
  const size_t oi = (((size_t)b * NCH + c) * DI + d) * DSn;
  float h[16];
#pragma unroll
  for (int j = 0; j < 16; j += 4) {
    const float4 hv = *reinterpret_cast<const float4*>(&Hin[oi + j]);
    h[j] = hv.x; h[j + 1] = hv.y; h[j + 2] = hv.z; h[j + 3] = hv.w;
  }

  for (int w = 0; w < 2; ++w) {
    const size_t twb = tbase + w * 16;
#pragma unroll
    for (int j = 0; j < 2; ++j) {  // dt, uc, z bf16 [16][128]
      const int k = j * 128 + tid;
      const int row = k >> 4, col = (k & 15) * 8;
      gload16(dtb + (twb + row) * DI + d0 + col, &s_dt[row * 128 + col]);
      gload16(uc + (twb + row) * DI + d0 + col, &s_uc[row * 128 + col]);
      gload16(xz + (twb + row) * (2 * DI) + DI + d0 + col, &s_z[row * 128 + col]);
    }
    {  // B|C [16][32] f32, all 128 threads
      gload16((const u16*)(xdbl + (twb + (tid >> 3)) * 96 + DTRk + (tid & 7) * 4),
              (u16*)&s_bc[tid * 4]);
    }
    __syncthreads();
#define P3_STEP(DA_STMT)                                                        \
    for (int tr = 0; tr < 16; ++tr) {                                           \
      const float dtv = bf2f(s_dt[tr * 128 + tid]);                             \
      const float uv = bf2f(s_uc[tr * 128 + tid]);                              \
      const float du = dtv * uv;                                                \
      float dA[16];                                                             \
      DA_STMT;                                                                  \
      float Bf[16], Cf[16];                                                     \
      _Pragma("unroll")                                                         \
      for (int j = 0; j < 16; j += 4) {                                         \
        const float4 Bv = *reinterpret_cast<const float4*>(&s_bc[tr * 32 + j]); \
        const float4 Cv = *reinterpret_cast<const float4*>(&s_bc[tr * 32 + 16 + j]); \
        Bf[j] = Bv.x; Bf[j + 1] = Bv.y; Bf[j + 2] = Bv.z; Bf[j + 3] = Bv.w;     \
        Cf[j] = Cv.x; Cf[j + 1] = Cv.y; Cf[j + 2] = Cv.z; Cf[j + 3] = Cv.w;     \
      }                                                                         \
      _Pragma("unroll")                                                         \
      for (int j = 0; j < 16; ++j) h[j] = dA[j] * h[j] + du * Bf[j];            \
      float y0 = 0.f, y1 = 0.f, y2 = 0.f, y3 = 0.f;                             \
      _Pragma("unroll")                                                         \
      for (int j = 0; j < 16; j += 4) {                                         \
        y0 += h[j] * Cf[j];                                                     \
        y1 += h[j + 1] * Cf[j + 1];                                             \
        y2 += h[j + 2] * Cf[j + 2];                                             \
        y3 += h[j + 3] * Cf[j + 3];                                             \
      }                                                                         \
      const float y = (y0 + y1) + (y2 + y3) + uv * Dd;                          \
      const float z = bf2f(s_z[tr * 128 + tid]);                                \
      const float sz = z / (1.f + __expf(-z));                                  \
      yb[(twb + tr) * DI + d] = f2bf(y * sz);                                   \
    }
    if (fastA) {
      P3_STEP(CALC_POWERS(dA, exp2f(-L2E * dtv)));
    } else {
      P3_STEP({ _Pragma("unroll") for (int j = 0; j < 16; ++j) dA[j] = exp2f(dtv * Av[j] * L2E); });
    }
#undef P3_STEP
    __syncthreads();
  }
}

extern "C" void kernel_launch(void* const* d_in, const int* in_sizes, int n_in,
                              void* d_out, int out_size, void* d_ws, size_t ws_size,
                              hipStream_t stream) {
  (void)in_sizes; (void)n_in; (void)out_size; (void)ws_size;
  const float* x      = (const float*)d_in[0];
  const float* norm_w = (const float*)d_in[1];
  const float* W_in   = (const float*)d_in[2];
  const float* W_conv = (const float*)d_in[3];
  const float* b_conv = (const float*)d_in[4];
  const float* W_xp   = (const float*)d_in[5];
  const float* W_dt   = (const float*)d_in[6];
  const float* b_dt   = (const float*)d_in[7];
  const float* A_log  = (const float*)d_in[8];
  const float* Dvec   = (const float*)d_in[9];
  const float* W_out  = (const float*)d_in[10];
  float* out = (float*)d_out;

  char* ws = (char*)d_ws;
  size_t off = 0;
  auto alloc = [&](size_t bytes) -> void* {
    void* p = ws + off;
    off += (bytes + 255) & ~(size_t)255;
    return p;
  };
  u16* Win_b  = (u16*)alloc((size_t)4096 * 1024 * 2);   // 8 MB (dead after in_proj)
  u16* Wout_b = (u16*)alloc((size_t)1024 * 2048 * 2);
  u16* Wxp_b  = (u16*)alloc((size_t)128 * 2048 * 2);
  u16* Wdt_b  = (u16*)alloc((size_t)2048 * 64 * 2);
  u16* xn_b   = (u16*)alloc((size_t)MR * DM * 2);       // 8 MB (dead after in_proj)
  u16* xz_b   = (u16*)alloc((size_t)MR * 2 * DI * 2);   // 32 MB
  u16* uc_b   = (u16*)alloc((size_t)MR * DI * 2);       // 16 MB
  float* xdbl = (float*)alloc((size_t)MR * 96 * 4);     // 1.5 MB
  u16* dtr_b  = (u16*)alloc((size_t)MR * 64 * 2);       // 0.5 MB
  u16* dtf_b  = (u16*)alloc((size_t)MR * DI * 2);       // 16 MB
  u16* y_b    = (u16*)alloc((size_t)MR * DI * 2);       // 16 MB; sdt aliases (dead before y write)
  float* Sbuf = (float*)alloc((size_t)2 * NCH * DI * DSn * 4);  // 16 MB
  float* part0 = (float*)Win_b;
  float* part1 = (float*)xn_b;
  float* sdtb = (float*)y_b;   // 1 MB; consumed by phase2 before phase3 writes y
  // out_proj partials: 2 x 8MB bf16, alias xz_b (dead after scan_phase3).
  u16* opart = (u16*)xz_b;

  // fused rmsnorm + weight converts (float4-wide)
  cvt_norm<<<MR, 256, 0, stream>>>(x, norm_w, W_in, W_out, W_dt, W_xp,
                                   xn_b, Win_b, Wout_b, Wdt_b, Wxp_b);

  // xz = xn @ W_in^T : [4096,4096] -- 128x256 tiles, 16x16x32 MFMA, 2 blocks/CU
  gemm128n256<0><<<dim3(16, 32, 1), 512, 0, stream>>>(xn_b, Win_b, MR, 4096, 1024, 1024,
                                                      xz_b);
  // depthwise conv + silu -> u_conv (8 ch/thread)
  conv_silu_kernel<<<4096, 256, 0, stream>>>(xz_b, W_conv, b_conv, uc_b);
  // x_dbl = u_conv @ W_xproj^T : [4096,96] via split-K(8) + reduce
  gemm_xproj_splitk<<<dim3(8, 32), 256, 0, stream>>>(uc_b, Wxp_b, part0, part1);
  xproj_reduce<<<2048, 256, 0, stream>>>(part0, part1, xdbl, dtr_b);
  // dt = softplus(dtr @ W_dt^T + b_dt) : [4096,2048] bf16
  gemm_dt<<<dim3(16, 32), 256, 0, stream>>>(dtr_b, Wdt_b, MR, 2048, 64, dtf_b, b_dt);
  // chunked selective scan: local scans -> compose (S:=Hin) -> rescan+gate
  scan_phase1<<<2048, 128, 0, stream>>>(dtf_b, xdbl, uc_b, A_log, sdtb, Sbuf);
  scan_phase2<<<128, 128, 0, stream>>>(A_log, sdtb, Sbuf);
  scan_phase3<<<2048, 128, 0, stream>>>(dtf_b, xdbl, uc_b, xz_b, A_log, Dvec,
                                        Sbuf, y_b);
  // out = y @ W_out^T + x : split-K=2, bf16 partials + fused reduce
  gemm128n256<1><<<dim3(4, 32, 2), 512, 0, stream>>>(y_b, Wout_b, MR, 1024, 2048, 1024,
                                                     opart);
  outproj_reduce2<<<2048, 256, 0, stream>>>(opart, x, out);
}